// Round 1
// baseline (195.204 us; speedup 1.0000x reference)
//
#include <hip/hip_runtime.h>
#include <math.h>

typedef __bf16 bf16;
typedef __attribute__((ext_vector_type(8))) __bf16 bf16x8;
typedef __attribute__((ext_vector_type(4))) float f32x4;
typedef unsigned short u16;
typedef unsigned int u32;

constexpr int Nn = 8, Cc = 512, Ll = 2048, Hh = 8, Dd = 64;
constexpr float kScale = 0.044194173824159216f;           // 512^-0.5
constexpr float kQexp2 = kScale * 1.44269504088896341f;   // fold log2(e) into Q
constexpr size_t NCL = (size_t)Nn * Cc * Ll;
constexpr size_t WSZ = (size_t)Cc * Cc;

static __device__ __forceinline__ u16 bfbits(bf16 v) {
    union { bf16 b; u16 u; } x; x.b = v; return x.u;
}
static __device__ __forceinline__ u32 fbits(float f) {
    union { float f; u32 u; } x; x.f = f; return x.u;
}
static __device__ __forceinline__ float fexp2(float x) {
#if __has_builtin(__builtin_amdgcn_exp2f)
    return __builtin_amdgcn_exp2f(x);
#else
    return exp2f(x);
#endif
}

#define MFMA(a, b, c) __builtin_amdgcn_mfma_f32_16x16x32_bf16((a), (b), (c), 0, 0, 0)

static __device__ __forceinline__ void async16(const bf16* g, bf16* l) {
    __builtin_amdgcn_global_load_lds(
        (const __attribute__((address_space(1))) void*)g,
        (__attribute__((address_space(3))) void*)l, 16, 0, 0);
}

// ---------------------------------------------------------------------------
// prep: z<8 -> x [n][c][l] fp32 -> xT [n][l][c] bf16 (64x64 tiles via LDS);
//       z==8 -> weights fp32 -> bf16.  grid (32, 8, 9), block 256.
// ---------------------------------------------------------------------------
__global__ __launch_bounds__(256) void prep_kernel(
    const float* __restrict__ x,
    const float* __restrict__ Wq, const float* __restrict__ Wk,
    const float* __restrict__ Wv, const float* __restrict__ Wo,
    bf16* __restrict__ xT, bf16* __restrict__ Wb)
{
    const int tid = threadIdx.x;
    if (blockIdx.z == Nn) {
        int gid = (blockIdx.y * 32 + blockIdx.x) * 256 + tid;   // 0..65535
        int w = gid >> 14;
        int o = (gid & 16383) * 4;                              // float4 base
        const float* src = (w == 0) ? Wq : (w == 1) ? Wk : (w == 2) ? Wv : Wo;
        bf16* dst = Wb + (size_t)w * WSZ;
#pragma unroll
        for (int j = 0; j < 4; j++) {
            float4 v = ((const float4*)src)[o + j];
            ushort4 u;
            u.x = bfbits((bf16)v.x); u.y = bfbits((bf16)v.y);
            u.z = bfbits((bf16)v.z); u.w = bfbits((bf16)v.w);
            *(ushort4*)(dst + (size_t)(o + j) * 4) = u;
        }
        return;
    }

    __shared__ bf16 Ts[64][72];
    const int lt = blockIdx.x, ct = blockIdx.y, n = blockIdx.z;

    const int cr = tid >> 2, l0 = (tid & 3) * 16;
    const float* src = x + ((size_t)(n * Cc + ct * 64 + cr)) * Ll + lt * 64 + l0;
#pragma unroll
    for (int i = 0; i < 4; i++) {
        float4 v = *(const float4*)(src + i * 4);
        Ts[l0 + i * 4 + 0][cr] = (bf16)v.x;
        Ts[l0 + i * 4 + 1][cr] = (bf16)v.y;
        Ts[l0 + i * 4 + 2][cr] = (bf16)v.z;
        Ts[l0 + i * 4 + 3][cr] = (bf16)v.w;
    }
    __syncthreads();

    const int lr = tid >> 2, c0 = (tid & 3) * 16;
    bf16* dst = xT + ((size_t)(n * Ll + lt * 64 + lr)) * Cc + ct * 64 + c0;
    *(bf16x8*)(dst)     = *(const bf16x8*)&Ts[lr][c0];
    *(bf16x8*)(dst + 8) = *(const bf16x8*)&Ts[lr][c0 + 8];
}

// ---------------------------------------------------------------------------
// QKV GEMM (m97 structure, unchanged). Q pre-scaled by kScale*log2e.
// ---------------------------------------------------------------------------
__global__ __launch_bounds__(256) void qkv_gemm(
    const bf16* __restrict__ xT, const bf16* __restrict__ Wb,
    bf16* __restrict__ Qt, bf16* __restrict__ Kt, bf16* __restrict__ Vb)
{
    const int lt = blockIdx.x, ow = blockIdx.y, n = blockIdx.z;
    const int widx = ow >> 2, otile = ow & 3;

    __shared__ bf16 Xs[128 * 64];
    __shared__ bf16 Ws[128 * 64];

    const int tid = threadIdx.x;
    const int lane = tid & 63, wv = tid >> 6;
    const int m = lane & 15, quad = lane >> 4;
    const int rh = wv & 1, ch = wv >> 1;

    const bf16* __restrict__ W = Wb + (size_t)widx * WSZ + (size_t)otile * 128 * Cc;
    const bf16* __restrict__ X = xT + (size_t)(n * Ll + lt * 128) * Cc;

    int srow[4], scol[4];
#pragma unroll
    for (int i = 0; i < 4; i++) {
        int q = i * 256 + tid;
        srow[i] = q >> 3;
        scol[i] = ((q ^ (q >> 3)) & 7) * 8;
    }

    f32x4 acc[4][4] = {};

    for (int c0 = 0; c0 < Cc; c0 += 64) {
#pragma unroll
        for (int i = 0; i < 4; i++)
            async16(&X[(size_t)srow[i] * Cc + c0 + scol[i]], &Xs[(i * 256 + tid) * 8]);
#pragma unroll
        for (int i = 0; i < 4; i++)
            async16(&W[(size_t)srow[i] * Cc + c0 + scol[i]], &Ws[(i * 256 + tid) * 8]);
        __syncthreads();

        const bf16* TA = (widx < 2) ? Xs : Ws;
        const bf16* TB = (widx < 2) ? Ws : Xs;
#pragma unroll
        for (int kk = 0; kk < 2; kk++) {
            const int sw = (((kk * 4 + quad) ^ (m & 7)) * 8);
            bf16x8 af[4], bfr[4];
#pragma unroll
            for (int t = 0; t < 4; t++)
                af[t] = *(const bf16x8*)&TA[(rh * 64 + t * 16 + m) * 64 + sw];
#pragma unroll
            for (int u = 0; u < 4; u++)
                bfr[u] = *(const bf16x8*)&TB[(ch * 64 + u * 16 + m) * 64 + sw];
#pragma unroll
            for (int t = 0; t < 4; t++)
#pragma unroll
                for (int u = 0; u < 4; u++)
                    acc[t][u] = MFMA(af[t], bfr[u], acc[t][u]);
        }
        __syncthreads();
    }

    if (widx < 2) {
        const float fq = (widx == 0) ? kQexp2 : 1.0f;
        bf16* __restrict__ OUT = (widx == 0) ? Qt : Kt;
#pragma unroll
        for (int u = 0; u < 4; u++) {
            const int o = otile * 128 + ch * 64 + u * 16 + m;
            const int h = o >> 6, d = o & 63;
            bf16* base = OUT + (size_t)(n * Hh + h) * Ll * Dd + d;
#pragma unroll
            for (int t = 0; t < 4; t++) {
                const int l0 = lt * 128 + rh * 64 + t * 16 + quad * 4;
#pragma unroll
                for (int r = 0; r < 4; r++)
                    base[(size_t)(l0 + r) * Dd] = (bf16)(acc[t][u][r] * fq);
            }
        }
    } else {
#pragma unroll
        for (int t = 0; t < 4; t++) {
            const int ob = otile * 128 + rh * 64 + t * 16 + quad * 4;
#pragma unroll
            for (int r = 0; r < 4; r++) {
                const int oo = ob + r, h = oo >> 6, d = oo & 63;
                bf16* base = Vb + ((size_t)(n * Hh + h) * Dd + d) * Ll;
#pragma unroll
                for (int u = 0; u < 4; u++)
                    base[lt * 128 + ch * 64 + u * 16 + m] = (bf16)acc[t][u][r];
            }
        }
    }
}

// ---------------------------------------------------------------------------
// Causal attention v8. LDS-BW-bound fix: 128-row supertiles, 4 waves x 32 q
// rows each, so the per-wave full K/V tile ds_reads amortize over 2x the
// output. Pairing {jp, 15-jp} -> uniform 34 k-iters per block. Grid
// (h, 8, n) = 512 blocks -> 2 blocks/CU, 48 KB LDS. Wave w diagonal tile is
// 2*st + (w>>1); waves 0,1 skip the supertile's last k-tile (wave-uniform).
// Single barrier per iter; async16 double-buffered K/V staging unchanged.
// ---------------------------------------------------------------------------
__global__ __launch_bounds__(256, 2) void attn_mfma(
    const bf16* __restrict__ Qt, const bf16* __restrict__ Kt,
    const bf16* __restrict__ Vb, bf16* __restrict__ AO)
{
    const int h  = blockIdx.x;
    const int jp = blockIdx.y;   // 0..7
    const int n  = blockIdx.z;

    __shared__ bf16 KV[2][2][64 * 64];   // [buf][K=0/V=1] 32 KB
    __shared__ bf16 Pbuf[4][32 * 64];    // per-wave P (32 q rows) 16 KB

    const int tid = threadIdx.x;
    const int lane = tid & 63, wv = tid >> 6;
    const int m = lane & 15, quad = lane >> 4;

    const size_t bnh = (size_t)(n * Hh + h) * Ll * Dd;
    const bf16* __restrict__ Qh = Qt + bnh;
    const bf16* __restrict__ Kh = Kt + bnh;
    const bf16* __restrict__ Vh = Vb + bnh;

    const int srow = tid >> 3;                           // 0..31 (and +32)
    const int scs  = (((tid & 7) ^ (srow & 7)) * 8);     // swizzled global chunk
    const int swz  = (m & 7);

    bf16* const Pw = &Pbuf[wv][0];

    bf16x8 ones;
#pragma unroll
    for (int j = 0; j < 8; j++) ones[j] = (bf16)1.0f;

    const int thr0 = (wv & 1) * 32;      // + g*16 per q-group
    const int doff = wv >> 1;            // diagonal k-tile offset in supertile
    int koff[4];
#pragma unroll
    for (int r = 0; r < 4; r++) koff[r] = quad * 4 + r - m;

#pragma unroll 1
    for (int ph = 0; ph < 2; ph++) {
        const int st = ph ? (15 - jp) : jp;          // supertile 0..15
        const int nk = 2 * st + 2;                   // k-tiles for this block
        const int dtile = 2 * st + doff;             // this wave's diag tile
        const int qrow0 = st * 128 + wv * 32;

        bf16x8 qf[2][2];
#pragma unroll
        for (int g = 0; g < 2; g++) {
            qf[g][0] = *(const bf16x8*)&Qh[(size_t)(qrow0 + g * 16 + m) * Dd + quad * 8];
            qf[g][1] = *(const bf16x8*)&Qh[(size_t)(qrow0 + g * 16 + m) * Dd + 32 + quad * 8];
        }

        f32x4 O[4][2] = {};
        f32x4 Ls[2] = {};

        // stage tile 0 -> buf 0
        async16(&Kh[(size_t)(srow) * Dd + scs],      &KV[0][0][(size_t)tid * 8]);
        async16(&Kh[(size_t)(srow + 32) * Dd + scs], &KV[0][0][(size_t)tid * 8 + 2048]);
        async16(&Vh[(size_t)srow * Ll + scs],        &KV[0][1][(size_t)tid * 8]);
        async16(&Vh[(size_t)(srow + 32) * Ll + scs], &KV[0][1][(size_t)tid * 8 + 2048]);
        __syncthreads();   // drains asyncs

        for (int kt = 0; kt < nk; kt++) {
            const int cur = kt & 1;

            if (kt + 1 < nk) {   // prefetch next tile into the other buffer
                const int kn = (kt + 1) * 64;
                async16(&Kh[(size_t)(kn + srow) * Dd + scs],      &KV[cur ^ 1][0][(size_t)tid * 8]);
                async16(&Kh[(size_t)(kn + srow + 32) * Dd + scs], &KV[cur ^ 1][0][(size_t)tid * 8 + 2048]);
                async16(&Vh[(size_t)srow * Ll + kn + scs],        &KV[cur ^ 1][1][(size_t)tid * 8]);
                async16(&Vh[(size_t)(srow + 32) * Ll + kn + scs], &KV[cur ^ 1][1][(size_t)tid * 8 + 2048]);
            }

            if (kt <= dtile) {   // wave-uniform: waves 0,1 skip last tile
                const bf16* Ks = &KV[cur][0][0];
                const bf16* Vs = &KV[cur][1][0];

                // ---- S^T = K x Q : lane (m,quad) St[t][g][r] =
                //      S[k=t*16+quad*4+r][q=qrow0+g*16+m]
                f32x4 St[4][2] = {};
#pragma unroll
                for (int t = 0; t < 4; t++) {
                    bf16x8 kf0 = *(const bf16x8*)&Ks[(t * 16 + m) * 64 + ((quad ^ swz) * 8)];
                    bf16x8 kf1 = *(const bf16x8*)&Ks[(t * 16 + m) * 64 + (((4 + quad) ^ swz) * 8)];
#pragma unroll
                    for (int g = 0; g < 2; g++) {
                        St[t][g] = MFMA(kf0, qf[g][0], St[t][g]);
                        St[t][g] = MFMA(kf1, qf[g][1], St[t][g]);
                    }
                }

                const bool dg = (kt == dtile);   // wave-uniform: diagonal tile
#pragma unroll
                for (int g = 0; g < 2; g++) {
                    const int thr = thr0 + g * 16;
#pragma unroll
                    for (int t = 0; t < 4; t++) {
                        float p0 = fexp2(St[t][g][0]);
                        float p1 = fexp2(St[t][g][1]);
                        float p2 = fexp2(St[t][g][2]);
                        float p3 = fexp2(St[t][g][3]);
                        if (dg) {
                            if (t * 16 + koff[0] > thr) p0 = 0.f;
                            if (t * 16 + koff[1] > thr) p1 = 0.f;
                            if (t * 16 + koff[2] > thr) p2 = 0.f;
                            if (t * 16 + koff[3] > thr) p3 = 0.f;
                        }
                        u32 pk0 = (fbits(p0) >> 16) | (fbits(p1) & 0xFFFF0000u);
                        u32 pk1 = (fbits(p2) >> 16) | (fbits(p3) & 0xFFFF0000u);
                        const int pidx = (g * 16 + m) * 64 +
                                         (((2 * t + (quad >> 1)) ^ swz) * 8) + (quad & 1) * 4;
                        *(uint2*)&Pw[pidx] = make_uint2(pk0, pk1);
                    }
                }
                asm volatile("s_waitcnt lgkmcnt(0)" ::: "memory");

                bf16x8 pf[2][2];
#pragma unroll
                for (int g = 0; g < 2; g++) {
                    pf[g][0] = *(const bf16x8*)&Pw[(g * 16 + m) * 64 + ((quad ^ swz) * 8)];
                    pf[g][1] = *(const bf16x8*)&Pw[(g * 16 + m) * 64 + (((4 + quad) ^ swz) * 8)];
                    Ls[g] = MFMA(pf[g][0], ones, Ls[g]);
                    Ls[g] = MFMA(pf[g][1], ones, Ls[g]);
                }
#pragma unroll
                for (int t = 0; t < 4; t++) {
                    bf16x8 vf0 = *(const bf16x8*)&Vs[(t * 16 + m) * 64 + ((quad ^ swz) * 8)];
                    bf16x8 vf1 = *(const bf16x8*)&Vs[(t * 16 + m) * 64 + (((4 + quad) ^ swz) * 8)];
#pragma unroll
                    for (int g = 0; g < 2; g++) {
                        O[t][g] = MFMA(pf[g][0], vf0, O[t][g]);
                        O[t][g] = MFMA(pf[g][1], vf1, O[t][g]);
                    }
                }
            }

            __syncthreads();   // single barrier: drains prefetch asyncs + flips buffers
        }

        // ---- epilogue: normalize (Ls in O-row layout), store AO[n][l][c] ----
        const size_t aobase = (size_t)n * Ll * Cc + (size_t)h * 64;
#pragma unroll
        for (int g = 0; g < 2; g++) {
            f32x4 inv;
#pragma unroll
            for (int r = 0; r < 4; r++) inv[r] = 1.0f / Ls[g][r];
#pragma unroll
            for (int t = 0; t < 4; t++)
#pragma unroll
                for (int r = 0; r < 4; r++) {
                    const int q = qrow0 + g * 16 + quad * 4 + r;
                    AO[aobase + (size_t)q * Cc + t * 16 + m] = (bf16)(O[t][g][r] * inv[r]);
                }
        }
    }
}

// ---------------------------------------------------------------------------
// Output GEMM (m97 structure, unchanged), fp32 out + bias.
// ---------------------------------------------------------------------------
__global__ __launch_bounds__(256) void out_gemm(
    const bf16* __restrict__ AO, const bf16* __restrict__ Wb,
    const float* __restrict__ bo, float* __restrict__ out)
{
    const int lt = blockIdx.x, ot = blockIdx.y, n = blockIdx.z;

    __shared__ bf16 Ws[128 * 64];
    __shared__ bf16 Bs[128 * 64];

    const int tid = threadIdx.x;
    const int lane = tid & 63, wv = tid >> 6;
    const int m = lane & 15, quad = lane >> 4;
    const int rh = wv & 1, ch = wv >> 1;

    const bf16* __restrict__ W = Wb + 3 * WSZ + (size_t)ot * 128 * Cc;
    const bf16* __restrict__ B = AO + (size_t)(n * Ll + lt * 128) * Cc;

    int srow[4], scol[4];
#pragma unroll
    for (int i = 0; i < 4; i++) {
        int q = i * 256 + tid;
        srow[i] = q >> 3;
        scol[i] = ((q ^ (q >> 3)) & 7) * 8;
    }

    f32x4 acc[4][4] = {};

    for (int c0 = 0; c0 < Cc; c0 += 64) {
#pragma unroll
        for (int i = 0; i < 4; i++)
            async16(&W[(size_t)srow[i] * Cc + c0 + scol[i]], &Ws[(i * 256 + tid) * 8]);
#pragma unroll
        for (int i = 0; i < 4; i++)
            async16(&B[(size_t)srow[i] * Cc + c0 + scol[i]], &Bs[(i * 256 + tid) * 8]);
        __syncthreads();

#pragma unroll
        for (int kk = 0; kk < 2; kk++) {
            const int sw = (((kk * 4 + quad) ^ (m & 7)) * 8);
            bf16x8 af[4], bfr[4];
#pragma unroll
            for (int t = 0; t < 4; t++)
                af[t] = *(const bf16x8*)&Ws[(rh * 64 + t * 16 + m) * 64 + sw];
#pragma unroll
            for (int u = 0; u < 4; u++)
                bfr[u] = *(const bf16x8*)&Bs[(ch * 64 + u * 16 + m) * 64 + sw];
#pragma unroll
            for (int t = 0; t < 4; t++)
#pragma unroll
                for (int u = 0; u < 4; u++)
                    acc[t][u] = MFMA(af[t], bfr[u], acc[t][u]);
        }
        __syncthreads();
    }

#pragma unroll
    for (int t = 0; t < 4; t++) {
        const int ob = ot * 128 + rh * 64 + t * 16 + quad * 4;
#pragma unroll
        for (int r = 0; r < 4; r++) {
            const int o = ob + r;
            const float b = bo[o];
            float* base = out + ((size_t)n * Cc + o) * Ll + lt * 128 + ch * 64;
#pragma unroll
            for (int u = 0; u < 4; u++)
                base[u * 16 + m] = acc[t][u][r] + b;
        }
    }
}

// ---------------------------------------------------------------------------
extern "C" void kernel_launch(void* const* d_in, const int* in_sizes, int n_in,
                              void* d_out, int out_size, void* d_ws, size_t ws_size,
                              hipStream_t stream)
{
    const float* x  = (const float*)d_in[0];
    const float* Wq = (const float*)d_in[1];
    const float* Wk = (const float*)d_in[2];
    const float* Wv = (const float*)d_in[3];
    const float* Wo = (const float*)d_in[4];
    const float* bo = (const float*)d_in[5];
    float* out = (float*)d_out;

    bf16* ws = (bf16*)d_ws;
    bf16* xT = ws;                        // [n][l][c]
    bf16* Wb = xT + NCL;                  // 4 x 512x512
    bf16* Qt = Wb + 4 * WSZ;              // [n][h][l][d]  (pre-scaled)
    bf16* Kt = Qt + NCL;                  // [n][h][l][d]
    bf16* Vb = Kt + NCL;                  // [n][h][d][l]
    bf16* AO = Vb + NCL;                  // [n][l][c]

    prep_kernel<<<dim3(32, 8, Nn + 1), 256, 0, stream>>>(x, Wq, Wk, Wv, Wo, xT, Wb);
    qkv_gemm<<<dim3(16, 12, Nn), 256, 0, stream>>>(xT, Wb, Qt, Kt, Vb);
    attn_mfma<<<dim3(Hh, 8, Nn), 256, 0, stream>>>(Qt, Kt, Vb, AO);
    out_gemm<<<dim3(16, 4, Nn), 256, 0, stream>>>(AO, Wb, bo, out);
}